// Round 4
// baseline (1143.340 us; speedup 1.0000x reference)
//
#include <hip/hip_runtime.h>
#include <hip/hip_bf16.h>
#include <stdint.h>
#include <math.h>

typedef unsigned short u16;
typedef __attribute__((ext_vector_type(8))) short frag8;   // 8 bf16 (4 VGPRs)
typedef __attribute__((ext_vector_type(4))) float f32x4;

#define Hdim 1024
#define Brows 4096
#define BM 64
#define BN 128
#define BK 64

// out element offsets (fp32 elements)
#define OUT_B_OFF  8388608   // next_b base
#define OUT_D_OFF 16777216   // next_depth
#define OUT_F_OFF 16781312   // f
#define OUT_J_OFF 16785408   // j

__device__ __forceinline__ u16 f2bf(float f) {
    union { float f; unsigned int i; } v; v.f = f;
    unsigned int r = v.i + 0x7fffu + ((v.i >> 16) & 1u);   // RNE
    return (u16)(r >> 16);
}

// ---------- segmented NT GEMM (fp32 in, bf16 MFMA, fp32 out) ----------
// C[b,n] = sum_k A[b,k] * W[n,k]; A split in K into up to 3 segments of 1024
// fp32 cols (own base/stride); W is (1024 x K) fp32 K-major. Inputs converted
// to bf16 (RNE) during LDS staging. Rows with gate[row]==ksel get
// outp[row*ostr+col] = acc (fp32).
__global__ __launch_bounds__(256)
void gemm_k(const float* __restrict__ a0, int as0,
            const float* __restrict__ a1p, int as1,
            const float* __restrict__ a2p, int as2,
            const float* __restrict__ W, int K,
            const int* __restrict__ gate, int ksel,
            float* __restrict__ outp, int ostr)
{
    __shared__ alignas(16) u16 lsA[BM * BK];
    __shared__ alignas(16) u16 lsB[BN * BK];

    const int tid  = threadIdx.x;
    const int lane = tid & 63;
    const int wv   = tid >> 6;
    const int wm   = wv >> 1, wn = wv & 1;     // 2x2 waves, each 32x64
    const int m0   = blockIdx.x * BM;
    const int n0   = blockIdx.y * BN;

    f32x4 acc[2][4];
#pragma unroll
    for (int i = 0; i < 2; ++i)
#pragma unroll
        for (int j = 0; j < 4; ++j) acc[i][j] = (f32x4){0.f, 0.f, 0.f, 0.f};

    const float* segp[3] = { a0, a1p, a2p };
    const int    segs[3] = { as0, as1, as2 };

    const int nkt = K / BK;
    for (int kt = 0; kt < nkt; ++kt) {
        const int seg = kt >> 4;              // 16 BK-tiles per 1024-col segment
        const int kl  = (kt & 15) * BK;
        const float* ab = segp[seg];
        const int astr  = segs[seg];

        // fp32 global -> registers
        float4 ra[4];                          // A: 64x64 fp32 = 1024 float4
        float4 rb[8];                          // B: 128x64 fp32 = 2048 float4
#pragma unroll
        for (int i = 0; i < 4; ++i) {
            int ch = i * 256 + tid;
            int r = ch >> 4, c = (ch & 15) * 4;
            ra[i] = *(const float4*)(ab + (size_t)(m0 + r) * astr + kl + c);
        }
#pragma unroll
        for (int i = 0; i < 8; ++i) {
            int ch = i * 256 + tid;
            int r = ch >> 4, c = (ch & 15) * 4;
            rb[i] = *(const float4*)(W + (size_t)(n0 + r) * K + kt * BK + c);
        }
        if (kt != 0) __syncthreads();
        // convert to bf16, store to LDS
#pragma unroll
        for (int i = 0; i < 4; ++i) {
            int ch = i * 256 + tid;
            int r = ch >> 4, c = (ch & 15) * 4;
            ushort4 h; h.x = f2bf(ra[i].x); h.y = f2bf(ra[i].y);
                       h.z = f2bf(ra[i].z); h.w = f2bf(ra[i].w);
            *(ushort4*)&lsA[r * BK + c] = h;
        }
#pragma unroll
        for (int i = 0; i < 8; ++i) {
            int ch = i * 256 + tid;
            int r = ch >> 4, c = (ch & 15) * 4;
            ushort4 h; h.x = f2bf(rb[i].x); h.y = f2bf(rb[i].y);
                       h.z = f2bf(rb[i].z); h.w = f2bf(rb[i].w);
            *(ushort4*)&lsB[r * BK + c] = h;
        }
        __syncthreads();

#pragma unroll
        for (int ks = 0; ks < 2; ++ks) {
            const int kc = ks * 32 + (lane >> 4) * 8;
            frag8 af[2], bfr[4];
#pragma unroll
            for (int i = 0; i < 2; ++i)
                af[i] = *(const frag8*)&lsA[(wm * 32 + i * 16 + (lane & 15)) * BK + kc];
#pragma unroll
            for (int j = 0; j < 4; ++j)
                bfr[j] = *(const frag8*)&lsB[(wn * 64 + j * 16 + (lane & 15)) * BK + kc];
#pragma unroll
            for (int i = 0; i < 2; ++i)
#pragma unroll
                for (int j = 0; j < 4; ++j)
                    acc[i][j] = __builtin_amdgcn_mfma_f32_16x16x32_bf16(af[i], bfr[j], acc[i][j], 0, 0, 0);
        }
    }
    __syncthreads();

    // D layout: row = quad*4 + reg, col = lane&15 (m89-verified)
    const int quad = lane >> 4;
    const int lcol = lane & 15;
#pragma unroll
    for (int i = 0; i < 2; ++i) {
#pragma unroll
        for (int r = 0; r < 4; ++r) {
            const int grow = m0 + wm * 32 + i * 16 + quad * 4 + r;
            if (gate[grow] == ksel) {
#pragma unroll
                for (int j = 0; j < 4; ++j) {
                    const int gcol = n0 + wn * 64 + j * 16 + lcol;
                    outp[(size_t)grow * ostr + gcol] = acc[i][j][r];
                }
            }
        }
    }
}

// ---------- prep_u: u_t[k] = sum_c w_b11[c,k] * w_att[t, 7168+c], t in {0,3} ----------
// u layout: u[0..2048) = t=0, u[2048..4096) = t=3. Requires u zeroed (atomics).
__global__ __launch_bounds__(256)
void prep_u(const float* __restrict__ w_b11, const float* __restrict__ w_att,
            float* __restrict__ u)
{
    const int k  = (blockIdx.x & 7) * 256 + threadIdx.x;   // 0..2047
    const int c0 = (blockIdx.x >> 3) * 128;                // 8 c-slices of 128
    float s0 = 0.f, s3 = 0.f;
    for (int c = c0; c < c0 + 128; ++c) {
        const float w = w_b11[(size_t)c * 2048 + k];
        s0 += w * w_att[7168 + c];
        s3 += w * w_att[3 * 8192 + 7168 + c];
    }
    atomicAdd(&u[k], s0);
    atomicAdd(&u[2048 + k], s3);
}

// ---------- decide: pure-fp32 logits, branch select, cheap outputs ----------
// pd==0: k=2 forced. pd==1: k = (s3>s0) ? 3 : 0 with
// s_t = a1·(w_t[2048+]+w_t[6144+]) + b1·w_t[3072+] + X·u_t[0:1024] + b1·u_t[1024:2048]
__global__ __launch_bounds__(256)
void decide(const float* __restrict__ X,
            const float* __restrict__ prev_a, const float* __restrict__ prev_b,
            const int* __restrict__ pdin,
            const float* __restrict__ w_att,
            const float* __restrict__ u,
            int* __restrict__ kbuf,
            float* __restrict__ out)
{
    const int lane = threadIdx.x & 63;
    const int wv   = threadIdx.x >> 6;
    const int b    = blockIdx.x * 4 + wv;
    const int pd   = pdin[b];

    const float* a1 = prev_a + (size_t)b * 2048 + 1024;
    const float* b1 = prev_b + (size_t)b * 2048 + 1024;
    const float* xr = X + (size_t)b * 1024;

    int k;
    float fv;
    if (pd == 0) {
        k = 2; fv = 1.f;
    } else {
        float d0 = 0.f, d3 = 0.f;
        const float* w0 = w_att;
        const float* w3 = w_att + 3 * 8192;
        const float* u0 = u;
        const float* u3 = u + 2048;
#pragma unroll
        for (int uu = 0; uu < 2; ++uu) {
            const int c = lane * 16 + uu * 8;
#pragma unroll
            for (int q = 0; q < 2; ++q) {
                const int cc = c + q * 4;
                float4 av = *(const float4*)&a1[cc];
                float4 bv = *(const float4*)&b1[cc];
                float4 xv = *(const float4*)&xr[cc];
                float4 wa0 = *(const float4*)&w0[2048 + cc];
                float4 wb0 = *(const float4*)&w0[3072 + cc];
                float4 wc0 = *(const float4*)&w0[6144 + cc];
                float4 wa3 = *(const float4*)&w3[2048 + cc];
                float4 wb3 = *(const float4*)&w3[3072 + cc];
                float4 wc3 = *(const float4*)&w3[6144 + cc];
                float4 ux0 = *(const float4*)&u0[cc];
                float4 ux3 = *(const float4*)&u3[cc];
                float4 ub0 = *(const float4*)&u0[1024 + cc];
                float4 ub3 = *(const float4*)&u3[1024 + cc];
                d0 += av.x*(wa0.x+wc0.x) + av.y*(wa0.y+wc0.y) + av.z*(wa0.z+wc0.z) + av.w*(wa0.w+wc0.w);
                d3 += av.x*(wa3.x+wc3.x) + av.y*(wa3.y+wc3.y) + av.z*(wa3.z+wc3.z) + av.w*(wa3.w+wc3.w);
                d0 += bv.x*wb0.x + bv.y*wb0.y + bv.z*wb0.z + bv.w*wb0.w;
                d3 += bv.x*wb3.x + bv.y*wb3.y + bv.z*wb3.z + bv.w*wb3.w;
                d0 += xv.x*ux0.x + xv.y*ux0.y + xv.z*ux0.z + xv.w*ux0.w;
                d3 += xv.x*ux3.x + xv.y*ux3.y + xv.z*ux3.z + xv.w*ux3.w;
                d0 += bv.x*ub0.x + bv.y*ub0.y + bv.z*ub0.z + bv.w*ub0.w;
                d3 += bv.x*ub3.x + bv.y*ub3.y + bv.z*ub3.z + bv.w*ub3.w;
            }
        }
#pragma unroll
        for (int off = 32; off; off >>= 1) {
            d0 += __shfl_xor(d0, off, 64);
            d3 += __shfl_xor(d3, off, 64);
        }
        k = (d3 > d0) ? 3 : 0;                 // np.argmax first-max tie -> 0
        fv = (k == 3) ? 1.f : 0.f;
    }
    const float jv = (pd == 0) ? 0.f : fv;     // j = f for pd==1, 0 for pd==0
    const int nd = (k == 2) ? pd + 1 : pd;

    float* outA = out;
    float* outB = out + OUT_B_OFF;

    const float4 z4 = make_float4(0.f, 0.f, 0.f, 0.f);
#pragma unroll
    for (int uu = 0; uu < 4; ++uu) {
        const int c = lane * 16 + uu * 4;
        *(float4*)&outA[(size_t)b * 2048 + c] = z4;   // next_a[:,0,:] = 0
        *(float4*)&outB[(size_t)b * 2048 + c] = z4;   // next_b[:,0,:] = 0
    }
    if (k == 3) {                                      // na11 = a1
#pragma unroll
        for (int uu = 0; uu < 4; ++uu) {
            const int c = lane * 16 + uu * 4;
            *(float4*)&outA[(size_t)b * 2048 + 1024 + c] = *(const float4*)&a1[c];
        }
    }
    if (lane == 0) {
        kbuf[b] = k;
        out[OUT_D_OFF + b] = (float)nd;
        out[OUT_F_OFF + b] = fv;
        out[OUT_J_OFF + b] = jv;
    }
}

// ---------- launch ----------
extern "C" void kernel_launch(void* const* d_in, const int* in_sizes, int n_in,
                              void* d_out, int out_size, void* d_ws, size_t ws_size,
                              hipStream_t stream)
{
    const float* X      = (const float*)d_in[0];
    const float* prev_a = (const float*)d_in[3];
    const float* prev_b = (const float*)d_in[4];
    const int*   pd     = (const int*)d_in[5];
    const float* w_a00  = (const float*)d_in[6];
    const float* w_a10  = (const float*)d_in[7];
    const float* w_b00  = (const float*)d_in[8];
    const float* w_b11  = (const float*)d_in[9];
    const float* w_b10  = (const float*)d_in[10];
    const float* w_att  = (const float*)d_in[12];

    // workspace: 32 KB total
    float* u    = (float*)d_ws;                        // 4096 fp32 = 16 KB
    int*   kbuf = (int*)((char*)d_ws + 16384);         // 4096 int32 = 16 KB

    const float* a1 = prev_a + 1024;   // stride 2048
    const float* b0 = prev_b;          // stride 2048
    const float* b1 = prev_b + 1024;   // stride 2048

    float* out   = (float*)d_out;
    float* outA1 = out + 1024;                 // next_a row-1, stride 2048
    float* outB1 = out + OUT_B_OFF + 1024;     // next_b row-1, stride 2048

    dim3 blk(256);
    dim3 grid(Brows / BM, Hdim / BN);

    hipMemsetAsync(u, 0, 16384, stream);
    prep_u<<<dim3(64), blk, 0, stream>>>(w_b11, w_att, u);
    decide<<<dim3(Brows / 4), blk, 0, stream>>>(X, prev_a, prev_b, pd, w_att, u, kbuf, out);

    // G1: next_a row1 = [X|b0|a1]@w_a00^T where k==0
    gemm_k<<<grid, blk, 0, stream>>>(X, 1024, b0, 2048, a1, 2048,
                                     w_a00, 3072, kbuf, 0, outA1, 2048);
    // G2: next_a row1 = [X|b0]@w_a10^T where k==2
    gemm_k<<<grid, blk, 0, stream>>>(X, 1024, b0, 2048, nullptr, 0,
                                     w_a10, 2048, kbuf, 2, outA1, 2048);
    // G3: next_b row1 = [X|b1]@w_b11^T where pd==1 (k==3 rows keep it;
    //     k==0 rows overwritten by G4)
    gemm_k<<<grid, blk, 0, stream>>>(X, 1024, b1, 2048, nullptr, 0,
                                     w_b11, 2048, pd, 1, outB1, 2048);
    // G4: next_b row1 = [X|a1|na00]@w_b00^T where k==0 (na00 staged from
    //     next_a row1 — all 4096 rows finite & written by decide/G1/G2)
    gemm_k<<<grid, blk, 0, stream>>>(X, 1024, a1, 2048, outA1, 2048,
                                     w_b00, 3072, kbuf, 0, outB1, 2048);
    // G5: next_b row1 = [X|na10]@w_b10^T where k==2
    gemm_k<<<grid, blk, 0, stream>>>(X, 1024, outA1, 2048, nullptr, 0,
                                     w_b10, 2048, kbuf, 2, outB1, 2048);
}

// Round 5
// 589.655 us; speedup vs baseline: 1.9390x; 1.9390x over previous
//
#include <hip/hip_runtime.h>
#include <hip/hip_bf16.h>
#include <stdint.h>
#include <math.h>

typedef unsigned short u16;
typedef __attribute__((ext_vector_type(8))) short frag8;   // 8 bf16 (4 VGPRs)
typedef __attribute__((ext_vector_type(4))) float f32x4;

#define Hdim 1024
#define Brows 4096
#define BM 64
#define BN 64
#define BK 64
#define LDK 72   // padded LDS row stride in u16 (144 B = 36 banks: kills 16-way conflicts)

// out element offsets (fp32 elements)
#define OUT_B_OFF  8388608   // next_b base
#define OUT_D_OFF 16777216   // next_depth
#define OUT_F_OFF 16781312   // f
#define OUT_J_OFF 16785408   // j

// packed RNE f32x2 -> bf16x2 (v_cvt_pk_bf16_f32 on gfx950)
__device__ __forceinline__ unsigned int pk2(float a, float b) {
    __hip_bfloat162 h = __float22bfloat162_rn(make_float2(a, b));
    union { __hip_bfloat162 h; unsigned int u; } v; v.h = h; return v.u;
}

// ---------- segmented NT GEMM (fp32 in, bf16 MFMA, fp32 out) ----------
// C[b,n] = sum_k A[b,k] * W[n,k]; A split in K into up to 3 segments of 1024
// fp32 cols (own base/stride); W is (1024 x K) fp32 K-major.
// Double-buffered LDS + register prefetch: global loads for tile kt+1 issue
// before the MFMA on tile kt (latency hidden); one barrier per iter.
// Rows with gate[row]==ksel get outp[row*ostr+col] = acc (fp32).
__global__ __launch_bounds__(256)
void gemm_k(const float* __restrict__ a0, int as0,
            const float* __restrict__ a1p, int as1,
            const float* __restrict__ a2p, int as2,
            const float* __restrict__ W, int K,
            const int* __restrict__ gate, int ksel,
            float* __restrict__ outp, int ostr)
{
    __shared__ alignas(16) u16 lsA[2][BM * LDK];
    __shared__ alignas(16) u16 lsB[2][BN * LDK];

    const int tid  = threadIdx.x;
    const int lane = tid & 63;
    const int wv   = tid >> 6;
    const int wm   = wv >> 1, wn = wv & 1;     // 2x2 waves, each 32x32
    const int m0   = blockIdx.x * BM;
    const int n0   = blockIdx.y * BN;

    const int lr = tid >> 4;            // 0..15 (row group for staging)
    const int lc = (tid & 15) * 4;      // fp32 col offset (16 thr/row x 4)

    f32x4 acc[2][2];
#pragma unroll
    for (int i = 0; i < 2; ++i)
#pragma unroll
        for (int j = 0; j < 2; ++j) acc[i][j] = (f32x4){0.f, 0.f, 0.f, 0.f};

    const float* segp[3] = { a0, a1p, a2p };
    const int    segs[3] = { as0, as1, as2 };

    const int nkt = K / BK;
    float4 ra[4], rb[4];

    // prologue: load tile 0 -> regs -> LDS[0]
    {
        const float* ab = segp[0];
        const int astr  = segs[0];
#pragma unroll
        for (int i = 0; i < 4; ++i) {
            const int r = i * 16 + lr;
            ra[i] = *(const float4*)(ab + (size_t)(m0 + r) * astr + lc);
            rb[i] = *(const float4*)(W  + (size_t)(n0 + r) * K + lc);
        }
#pragma unroll
        for (int i = 0; i < 4; ++i) {
            const int r = i * 16 + lr;
            uint2 ha = { pk2(ra[i].x, ra[i].y), pk2(ra[i].z, ra[i].w) };
            uint2 hb = { pk2(rb[i].x, rb[i].y), pk2(rb[i].z, rb[i].w) };
            *(uint2*)&lsA[0][r * LDK + lc] = ha;
            *(uint2*)&lsB[0][r * LDK + lc] = hb;
        }
    }
    __syncthreads();

    for (int kt = 0; kt < nkt; ++kt) {
        const int cur = kt & 1;
        const int nxt = cur ^ 1;
        const bool more = (kt + 1 < nkt);

        // issue global loads for tile kt+1 (latency hidden behind MFMA)
        if (more) {
            const int kn  = kt + 1;
            const int seg = kn >> 4;            // 16 BK-tiles per 1024-col segment
            const int kl  = (kn & 15) * BK;
            const float* ab = segp[seg];
            const int astr  = segs[seg];
#pragma unroll
            for (int i = 0; i < 4; ++i) {
                const int r = i * 16 + lr;
                ra[i] = *(const float4*)(ab + (size_t)(m0 + r) * astr + kl + lc);
                rb[i] = *(const float4*)(W  + (size_t)(n0 + r) * K + kn * BK + lc);
            }
        }

        // MFMA on LDS[cur]
#pragma unroll
        for (int ks = 0; ks < 2; ++ks) {
            const int kc = ks * 32 + (lane >> 4) * 8;
            frag8 af[2], bfr[2];
#pragma unroll
            for (int i = 0; i < 2; ++i)
                af[i] = *(const frag8*)&lsA[cur][(wm * 32 + i * 16 + (lane & 15)) * LDK + kc];
#pragma unroll
            for (int j = 0; j < 2; ++j)
                bfr[j] = *(const frag8*)&lsB[cur][(wn * 32 + j * 16 + (lane & 15)) * LDK + kc];
#pragma unroll
            for (int i = 0; i < 2; ++i)
#pragma unroll
                for (int j = 0; j < 2; ++j)
                    acc[i][j] = __builtin_amdgcn_mfma_f32_16x16x32_bf16(af[i], bfr[j], acc[i][j], 0, 0, 0);
        }

        if (more) {
            // convert + store into the other buffer, then one barrier
#pragma unroll
            for (int i = 0; i < 4; ++i) {
                const int r = i * 16 + lr;
                uint2 ha = { pk2(ra[i].x, ra[i].y), pk2(ra[i].z, ra[i].w) };
                uint2 hb = { pk2(rb[i].x, rb[i].y), pk2(rb[i].z, rb[i].w) };
                *(uint2*)&lsA[nxt][r * LDK + lc] = ha;
                *(uint2*)&lsB[nxt][r * LDK + lc] = hb;
            }
            __syncthreads();
        }
    }

    // D layout: row = quad*4 + reg, col = lane&15 (m89-verified)
    const int quad = lane >> 4;
    const int lcol = lane & 15;
#pragma unroll
    for (int i = 0; i < 2; ++i) {
#pragma unroll
        for (int r = 0; r < 4; ++r) {
            const int grow = m0 + wm * 32 + i * 16 + quad * 4 + r;
            if (gate[grow] == ksel) {
#pragma unroll
                for (int j = 0; j < 2; ++j) {
                    const int gcol = n0 + wn * 32 + j * 16 + lcol;
                    outp[(size_t)grow * ostr + gcol] = acc[i][j][r];
                }
            }
        }
    }
}

// ---------- prep_u: u_t[k] = sum_c w_b11[c,k] * w_att[t, 7168+c], t in {0,3} ----------
__global__ __launch_bounds__(256)
void prep_u(const float* __restrict__ w_b11, const float* __restrict__ w_att,
            float* __restrict__ u)
{
    const int k  = (blockIdx.x & 7) * 256 + threadIdx.x;   // 0..2047
    const int c0 = (blockIdx.x >> 3) * 128;                // 8 c-slices of 128
    float s0 = 0.f, s3 = 0.f;
    for (int c = c0; c < c0 + 128; ++c) {
        const float w = w_b11[(size_t)c * 2048 + k];
        s0 += w * w_att[7168 + c];
        s3 += w * w_att[3 * 8192 + 7168 + c];
    }
    atomicAdd(&u[k], s0);
    atomicAdd(&u[2048 + k], s3);
}

// ---------- decide: pure-fp32 logits, branch select, cheap outputs ----------
__global__ __launch_bounds__(256)
void decide(const float* __restrict__ X,
            const float* __restrict__ prev_a, const float* __restrict__ prev_b,
            const int* __restrict__ pdin,
            const float* __restrict__ w_att,
            const float* __restrict__ u,
            int* __restrict__ kbuf,
            float* __restrict__ out)
{
    const int lane = threadIdx.x & 63;
    const int wv   = threadIdx.x >> 6;
    const int b    = blockIdx.x * 4 + wv;
    const int pd   = pdin[b];

    const float* a1 = prev_a + (size_t)b * 2048 + 1024;
    const float* b1 = prev_b + (size_t)b * 2048 + 1024;
    const float* xr = X + (size_t)b * 1024;

    int k;
    float fv;
    if (pd == 0) {
        k = 2; fv = 1.f;
    } else {
        float d0 = 0.f, d3 = 0.f;
        const float* w0 = w_att;
        const float* w3 = w_att + 3 * 8192;
        const float* u0 = u;
        const float* u3 = u + 2048;
#pragma unroll
        for (int uu = 0; uu < 2; ++uu) {
            const int c = lane * 16 + uu * 8;
#pragma unroll
            for (int q = 0; q < 2; ++q) {
                const int cc = c + q * 4;
                float4 av = *(const float4*)&a1[cc];
                float4 bv = *(const float4*)&b1[cc];
                float4 xv = *(const float4*)&xr[cc];
                float4 wa0 = *(const float4*)&w0[2048 + cc];
                float4 wb0 = *(const float4*)&w0[3072 + cc];
                float4 wc0 = *(const float4*)&w0[6144 + cc];
                float4 wa3 = *(const float4*)&w3[2048 + cc];
                float4 wb3 = *(const float4*)&w3[3072 + cc];
                float4 wc3 = *(const float4*)&w3[6144 + cc];
                float4 ux0 = *(const float4*)&u0[cc];
                float4 ux3 = *(const float4*)&u3[cc];
                float4 ub0 = *(const float4*)&u0[1024 + cc];
                float4 ub3 = *(const float4*)&u3[1024 + cc];
                d0 += av.x*(wa0.x+wc0.x) + av.y*(wa0.y+wc0.y) + av.z*(wa0.z+wc0.z) + av.w*(wa0.w+wc0.w);
                d3 += av.x*(wa3.x+wc3.x) + av.y*(wa3.y+wc3.y) + av.z*(wa3.z+wc3.z) + av.w*(wa3.w+wc3.w);
                d0 += bv.x*wb0.x + bv.y*wb0.y + bv.z*wb0.z + bv.w*wb0.w;
                d3 += bv.x*wb3.x + bv.y*wb3.y + bv.z*wb3.z + bv.w*wb3.w;
                d0 += xv.x*ux0.x + xv.y*ux0.y + xv.z*ux0.z + xv.w*ux0.w;
                d3 += xv.x*ux3.x + xv.y*ux3.y + xv.z*ux3.z + xv.w*ux3.w;
                d0 += bv.x*ub0.x + bv.y*ub0.y + bv.z*ub0.z + bv.w*ub0.w;
                d3 += bv.x*ub3.x + bv.y*ub3.y + bv.z*ub3.z + bv.w*ub3.w;
            }
        }
#pragma unroll
        for (int off = 32; off; off >>= 1) {
            d0 += __shfl_xor(d0, off, 64);
            d3 += __shfl_xor(d3, off, 64);
        }
        k = (d3 > d0) ? 3 : 0;                 // np.argmax first-max tie -> 0
        fv = (k == 3) ? 1.f : 0.f;
    }
    const float jv = (pd == 0) ? 0.f : fv;
    const int nd = (k == 2) ? pd + 1 : pd;

    float* outA = out;
    float* outB = out + OUT_B_OFF;

    const float4 z4 = make_float4(0.f, 0.f, 0.f, 0.f);
#pragma unroll
    for (int uu = 0; uu < 4; ++uu) {
        const int c = lane * 16 + uu * 4;
        *(float4*)&outA[(size_t)b * 2048 + c] = z4;   // next_a[:,0,:] = 0
        *(float4*)&outB[(size_t)b * 2048 + c] = z4;   // next_b[:,0,:] = 0
    }
    if (k == 3) {                                      // na11 = a1
#pragma unroll
        for (int uu = 0; uu < 4; ++uu) {
            const int c = lane * 16 + uu * 4;
            *(float4*)&outA[(size_t)b * 2048 + 1024 + c] = *(const float4*)&a1[c];
        }
    }
    if (lane == 0) {
        kbuf[b] = k;
        out[OUT_D_OFF + b] = (float)nd;
        out[OUT_F_OFF + b] = fv;
        out[OUT_J_OFF + b] = jv;
    }
}

// ---------- launch ----------
extern "C" void kernel_launch(void* const* d_in, const int* in_sizes, int n_in,
                              void* d_out, int out_size, void* d_ws, size_t ws_size,
                              hipStream_t stream)
{
    const float* X      = (const float*)d_in[0];
    const float* prev_a = (const float*)d_in[3];
    const float* prev_b = (const float*)d_in[4];
    const int*   pd     = (const int*)d_in[5];
    const float* w_a00  = (const float*)d_in[6];
    const float* w_a10  = (const float*)d_in[7];
    const float* w_b00  = (const float*)d_in[8];
    const float* w_b11  = (const float*)d_in[9];
    const float* w_b10  = (const float*)d_in[10];
    const float* w_att  = (const float*)d_in[12];

    // workspace: 32 KB total
    float* u    = (float*)d_ws;                        // 4096 fp32 = 16 KB
    int*   kbuf = (int*)((char*)d_ws + 16384);         // 4096 int32 = 16 KB

    const float* a1 = prev_a + 1024;   // stride 2048
    const float* b0 = prev_b;          // stride 2048
    const float* b1 = prev_b + 1024;   // stride 2048

    float* out   = (float*)d_out;
    float* outA1 = out + 1024;                 // next_a row-1, stride 2048
    float* outB1 = out + OUT_B_OFF + 1024;     // next_b row-1, stride 2048

    dim3 blk(256);
    dim3 grid(Brows / BM, Hdim / BN);

    hipMemsetAsync(u, 0, 16384, stream);
    prep_u<<<dim3(64), blk, 0, stream>>>(w_b11, w_att, u);
    decide<<<dim3(Brows / 4), blk, 0, stream>>>(X, prev_a, prev_b, pd, w_att, u, kbuf, out);

    // G1: next_a row1 = [X|b0|a1]@w_a00^T where k==0
    gemm_k<<<grid, blk, 0, stream>>>(X, 1024, b0, 2048, a1, 2048,
                                     w_a00, 3072, kbuf, 0, outA1, 2048);
    // G2: next_a row1 = [X|b0]@w_a10^T where k==2
    gemm_k<<<grid, blk, 0, stream>>>(X, 1024, b0, 2048, nullptr, 0,
                                     w_a10, 2048, kbuf, 2, outA1, 2048);
    // G3: next_b row1 = [X|b1]@w_b11^T where pd==1 (k==3 keep; k==0 overwritten by G4)
    gemm_k<<<grid, blk, 0, stream>>>(X, 1024, b1, 2048, nullptr, 0,
                                     w_b11, 2048, pd, 1, outB1, 2048);
    // G4: next_b row1 = [X|a1|na00]@w_b00^T where k==0 (na00 staged from next_a row1)
    gemm_k<<<grid, blk, 0, stream>>>(X, 1024, a1, 2048, outA1, 2048,
                                     w_b00, 3072, kbuf, 0, outB1, 2048);
    // G5: next_b row1 = [X|na10]@w_b10^T where k==2
    gemm_k<<<grid, blk, 0, stream>>>(X, 1024, outA1, 2048, nullptr, 0,
                                     w_b10, 2048, kbuf, 2, outB1, 2048);
}

// Round 6
// 544.586 us; speedup vs baseline: 2.0995x; 1.0828x over previous
//
#include <hip/hip_runtime.h>
#include <hip/hip_bf16.h>
#include <stdint.h>
#include <math.h>

typedef unsigned short u16;
typedef __attribute__((ext_vector_type(8))) short frag8;   // 8 bf16 (4 VGPRs)
typedef __attribute__((ext_vector_type(4))) float f32x4;

#define Hdim 1024
#define Brows 4096
#define BM 128
#define BN 64
#define BK 64
#define LDK 72   // padded LDS row stride in u16 (144 B): 16-way -> free 2-way

// out element offsets (fp32 elements)
#define OUT_B_OFF  8388608   // next_b base
#define OUT_D_OFF 16777216   // next_depth
#define OUT_F_OFF 16781312   // f
#define OUT_J_OFF 16785408   // j

// packed RNE f32x2 -> bf16x2 (v_cvt_pk_bf16_f32 on gfx950)
__device__ __forceinline__ unsigned int pk2(float a, float b) {
    __hip_bfloat162 h = __float22bfloat162_rn(make_float2(a, b));
    union { __hip_bfloat162 h; unsigned int u; } v; v.h = h; return v.u;
}

struct RegTile { float4 a[8]; float4 b[4]; };   // per-thread staged fp32 tile

__device__ __forceinline__ void load_tile(RegTile& s,
        const float* const* segp, const int* segs,
        const float* __restrict__ W, int K, int kn,
        int m0, int n0, int lr, int lc)
{
    const int seg = kn >> 4;               // 16 BK-tiles per 1024-col segment
    const int kl  = (kn & 15) * BK;
    const float* ab = segp[seg];
    const int astr  = segs[seg];
#pragma unroll
    for (int i = 0; i < 8; ++i)
        s.a[i] = *(const float4*)(ab + (size_t)(m0 + i * 16 + lr) * astr + kl + lc);
#pragma unroll
    for (int i = 0; i < 4; ++i)
        s.b[i] = *(const float4*)(W + (size_t)(n0 + i * 16 + lr) * K + kn * BK + lc);
}

__device__ __forceinline__ void stage_tile(const RegTile& s, u16* LA, u16* LB,
                                           int lr, int lc)
{
#pragma unroll
    for (int i = 0; i < 8; ++i) {
        uint2 h = { pk2(s.a[i].x, s.a[i].y), pk2(s.a[i].z, s.a[i].w) };
        *(uint2*)&LA[(i * 16 + lr) * LDK + lc] = h;
    }
#pragma unroll
    for (int i = 0; i < 4; ++i) {
        uint2 h = { pk2(s.b[i].x, s.b[i].y), pk2(s.b[i].z, s.b[i].w) };
        *(uint2*)&LB[(i * 16 + lr) * LDK + lc] = h;
    }
}

__device__ __forceinline__ void do_mfma(const u16* LA, const u16* LB,
                                        int wm, int wn, int lane, f32x4 acc[4][2])
{
#pragma unroll
    for (int ks = 0; ks < 2; ++ks) {
        const int kc = ks * 32 + (lane >> 4) * 8;
        frag8 af[4], bf[2];
#pragma unroll
        for (int i = 0; i < 4; ++i)
            af[i] = *(const frag8*)&LA[(wm * 64 + i * 16 + (lane & 15)) * LDK + kc];
#pragma unroll
        for (int j = 0; j < 2; ++j)
            bf[j] = *(const frag8*)&LB[(wn * 32 + j * 16 + (lane & 15)) * LDK + kc];
#pragma unroll
        for (int i = 0; i < 4; ++i)
#pragma unroll
            for (int j = 0; j < 2; ++j)
                acc[i][j] = __builtin_amdgcn_mfma_f32_16x16x32_bf16(af[i], bf[j], acc[i][j], 0, 0, 0);
    }
}

// ---------- segmented NT GEMM (fp32 in, bf16 MFMA, fp32 out) ----------
// C[b,n] = sum_k A[b,k] * W[n,k]; A split in K into up to 3 segments of 1024
// fp32 cols (own base/stride); W is (1024 x K) fp32 K-major.
// 2-deep register pipeline + double-buffered LDS: loads for kt+2 in flight
// while kt+1 is converted and kt is in MFMA (load-latency window = 2 iters).
// Rows with gate[row]==ksel get outp[row*ostr+col] = acc (fp32).
__global__ __launch_bounds__(256)
void gemm_k(const float* __restrict__ a0, int as0,
            const float* __restrict__ a1p, int as1,
            const float* __restrict__ a2p, int as2,
            const float* __restrict__ W, int K,
            const int* __restrict__ gate, int ksel,
            float* __restrict__ outp, int ostr)
{
    __shared__ alignas(16) u16 lsA[2][BM * LDK];
    __shared__ alignas(16) u16 lsB[2][BN * LDK];

    const int tid  = threadIdx.x;
    const int lane = tid & 63;
    const int wv   = tid >> 6;
    const int wm   = wv >> 1, wn = wv & 1;     // 2x2 waves: 64x32 each
    const int m0   = blockIdx.x * BM;
    const int n0   = blockIdx.y * BN;

    const int lr = tid >> 4;            // 0..15 (staging row group)
    const int lc = (tid & 15) * 4;      // fp32 col offset

    f32x4 acc[4][2];
#pragma unroll
    for (int i = 0; i < 4; ++i)
#pragma unroll
        for (int j = 0; j < 2; ++j) acc[i][j] = (f32x4){0.f, 0.f, 0.f, 0.f};

    const float* segp[3] = { a0, a1p, a2p };
    const int    segs[3] = { as0, as1, as2 };

    const int nkt = K / BK;             // 32 or 48 (even)
    RegTile S0, S1;

    load_tile(S0, segp, segs, W, K, 0, m0, n0, lr, lc);
    load_tile(S1, segp, segs, W, K, 1, m0, n0, lr, lc);
    stage_tile(S0, lsA[0], lsB[0], lr, lc);
    __syncthreads();

    for (int kt = 0; kt < nkt; kt += 2) {
        // even sub-iter: compute LDS[0] (tile kt); S1 holds kt+1
        if (kt + 2 < nkt) load_tile(S0, segp, segs, W, K, kt + 2, m0, n0, lr, lc);
        do_mfma(lsA[0], lsB[0], wm, wn, lane, acc);
        stage_tile(S1, lsA[1], lsB[1], lr, lc);    // kt+1 -> LDS[1]
        __syncthreads();

        // odd sub-iter: compute LDS[1] (tile kt+1); S0 holds kt+2
        if (kt + 3 < nkt) load_tile(S1, segp, segs, W, K, kt + 3, m0, n0, lr, lc);
        do_mfma(lsA[1], lsB[1], wm, wn, lane, acc);
        if (kt + 2 < nkt) {
            stage_tile(S0, lsA[0], lsB[0], lr, lc); // kt+2 -> LDS[0]
            __syncthreads();
        }
    }

    // D layout: row = quad*4 + reg, col = lane&15 (m89-verified)
    const int quad = lane >> 4;
    const int lcol = lane & 15;
#pragma unroll
    for (int i = 0; i < 4; ++i) {
#pragma unroll
        for (int r = 0; r < 4; ++r) {
            const int grow = m0 + wm * 64 + i * 16 + quad * 4 + r;
            if (gate[grow] == ksel) {
#pragma unroll
                for (int j = 0; j < 2; ++j) {
                    const int gcol = n0 + wn * 32 + j * 16 + lcol;
                    outp[(size_t)grow * ostr + gcol] = acc[i][j][r];
                }
            }
        }
    }
}

// ---------- prep_u: u_t[k] = sum_c w_b11[c,k] * w_att[t, 7168+c], t in {0,3} ----------
__global__ __launch_bounds__(256)
void prep_u(const float* __restrict__ w_b11, const float* __restrict__ w_att,
            float* __restrict__ u)
{
    const int k  = (blockIdx.x & 7) * 256 + threadIdx.x;   // 0..2047
    const int c0 = (blockIdx.x >> 3) * 128;                // 8 c-slices of 128
    float s0 = 0.f, s3 = 0.f;
    for (int c = c0; c < c0 + 128; ++c) {
        const float w = w_b11[(size_t)c * 2048 + k];
        s0 += w * w_att[7168 + c];
        s3 += w * w_att[3 * 8192 + 7168 + c];
    }
    atomicAdd(&u[k], s0);
    atomicAdd(&u[2048 + k], s3);
}

// ---------- decide: pure-fp32 logits, branch select, cheap outputs ----------
__global__ __launch_bounds__(256)
void decide(const float* __restrict__ X,
            const float* __restrict__ prev_a, const float* __restrict__ prev_b,
            const int* __restrict__ pdin,
            const float* __restrict__ w_att,
            const float* __restrict__ u,
            int* __restrict__ kbuf,
            float* __restrict__ out)
{
    const int lane = threadIdx.x & 63;
    const int wv   = threadIdx.x >> 6;
    const int b    = blockIdx.x * 4 + wv;
    const int pd   = pdin[b];

    const float* a1 = prev_a + (size_t)b * 2048 + 1024;
    const float* b1 = prev_b + (size_t)b * 2048 + 1024;
    const float* xr = X + (size_t)b * 1024;

    int k;
    float fv;
    if (pd == 0) {
        k = 2; fv = 1.f;
    } else {
        float d0 = 0.f, d3 = 0.f;
        const float* w0 = w_att;
        const float* w3 = w_att + 3 * 8192;
        const float* u0 = u;
        const float* u3 = u + 2048;
#pragma unroll
        for (int uu = 0; uu < 2; ++uu) {
            const int c = lane * 16 + uu * 8;
#pragma unroll
            for (int q = 0; q < 2; ++q) {
                const int cc = c + q * 4;
                float4 av = *(const float4*)&a1[cc];
                float4 bv = *(const float4*)&b1[cc];
                float4 xv = *(const float4*)&xr[cc];
                float4 wa0 = *(const float4*)&w0[2048 + cc];
                float4 wb0 = *(const float4*)&w0[3072 + cc];
                float4 wc0 = *(const float4*)&w0[6144 + cc];
                float4 wa3 = *(const float4*)&w3[2048 + cc];
                float4 wb3 = *(const float4*)&w3[3072 + cc];
                float4 wc3 = *(const float4*)&w3[6144 + cc];
                float4 ux0 = *(const float4*)&u0[cc];
                float4 ux3 = *(const float4*)&u3[cc];
                float4 ub0 = *(const float4*)&u0[1024 + cc];
                float4 ub3 = *(const float4*)&u3[1024 + cc];
                d0 += av.x*(wa0.x+wc0.x) + av.y*(wa0.y+wc0.y) + av.z*(wa0.z+wc0.z) + av.w*(wa0.w+wc0.w);
                d3 += av.x*(wa3.x+wc3.x) + av.y*(wa3.y+wc3.y) + av.z*(wa3.z+wc3.z) + av.w*(wa3.w+wc3.w);
                d0 += bv.x*wb0.x + bv.y*wb0.y + bv.z*wb0.z + bv.w*wb0.w;
                d3 += bv.x*wb3.x + bv.y*wb3.y + bv.z*wb3.z + bv.w*wb3.w;
                d0 += xv.x*ux0.x + xv.y*ux0.y + xv.z*ux0.z + xv.w*ux0.w;
                d3 += xv.x*ux3.x + xv.y*ux3.y + xv.z*ux3.z + xv.w*ux3.w;
                d0 += bv.x*ub0.x + bv.y*ub0.y + bv.z*ub0.z + bv.w*ub0.w;
                d3 += bv.x*ub3.x + bv.y*ub3.y + bv.z*ub3.z + bv.w*ub3.w;
            }
        }
#pragma unroll
        for (int off = 32; off; off >>= 1) {
            d0 += __shfl_xor(d0, off, 64);
            d3 += __shfl_xor(d3, off, 64);
        }
        k = (d3 > d0) ? 3 : 0;                 // np.argmax first-max tie -> 0
        fv = (k == 3) ? 1.f : 0.f;
    }
    const float jv = (pd == 0) ? 0.f : fv;
    const int nd = (k == 2) ? pd + 1 : pd;

    float* outA = out;
    float* outB = out + OUT_B_OFF;

    const float4 z4 = make_float4(0.f, 0.f, 0.f, 0.f);
#pragma unroll
    for (int uu = 0; uu < 4; ++uu) {
        const int c = lane * 16 + uu * 4;
        *(float4*)&outA[(size_t)b * 2048 + c] = z4;   // next_a[:,0,:] = 0
        *(float4*)&outB[(size_t)b * 2048 + c] = z4;   // next_b[:,0,:] = 0
    }
    if (k == 3) {                                      // na11 = a1
#pragma unroll
        for (int uu = 0; uu < 4; ++uu) {
            const int c = lane * 16 + uu * 4;
            *(float4*)&outA[(size_t)b * 2048 + 1024 + c] = *(const float4*)&a1[c];
        }
    }
    if (lane == 0) {
        kbuf[b] = k;
        out[OUT_D_OFF + b] = (float)nd;
        out[OUT_F_OFF + b] = fv;
        out[OUT_J_OFF + b] = jv;
    }
}

// ---------- launch ----------
extern "C" void kernel_launch(void* const* d_in, const int* in_sizes, int n_in,
                              void* d_out, int out_size, void* d_ws, size_t ws_size,
                              hipStream_t stream)
{
    const float* X      = (const float*)d_in[0];
    const float* prev_a = (const float*)d_in[3];
    const float* prev_b = (const float*)d_in[4];
    const int*   pd     = (const int*)d_in[5];
    const float* w_a00  = (const float*)d_in[6];
    const float* w_a10  = (const float*)d_in[7];
    const float* w_b00  = (const float*)d_in[8];
    const float* w_b11  = (const float*)d_in[9];
    const float* w_b10  = (const float*)d_in[10];
    const float* w_att  = (const float*)d_in[12];

    // workspace: 32 KB total
    float* u    = (float*)d_ws;                        // 4096 fp32 = 16 KB
    int*   kbuf = (int*)((char*)d_ws + 16384);         // 4096 int32 = 16 KB

    const float* a1 = prev_a + 1024;   // stride 2048
    const float* b0 = prev_b;          // stride 2048
    const float* b1 = prev_b + 1024;   // stride 2048

    float* out   = (float*)d_out;
    float* outA1 = out + 1024;                 // next_a row-1, stride 2048
    float* outB1 = out + OUT_B_OFF + 1024;     // next_b row-1, stride 2048

    dim3 blk(256);
    dim3 grid(Brows / BM, Hdim / BN);

    hipMemsetAsync(u, 0, 16384, stream);
    prep_u<<<dim3(64), blk, 0, stream>>>(w_b11, w_att, u);
    decide<<<dim3(Brows / 4), blk, 0, stream>>>(X, prev_a, prev_b, pd, w_att, u, kbuf, out);

    // G1: next_a row1 = [X|b0|a1]@w_a00^T where k==0
    gemm_k<<<grid, blk, 0, stream>>>(X, 1024, b0, 2048, a1, 2048,
                                     w_a00, 3072, kbuf, 0, outA1, 2048);
    // G2: next_a row1 = [X|b0]@w_a10^T where k==2
    gemm_k<<<grid, blk, 0, stream>>>(X, 1024, b0, 2048, nullptr, 0,
                                     w_a10, 2048, kbuf, 2, outA1, 2048);
    // G3: next_b row1 = [X|b1]@w_b11^T where pd==1 (k==3 keep; k==0 overwritten by G4)
    gemm_k<<<grid, blk, 0, stream>>>(X, 1024, b1, 2048, nullptr, 0,
                                     w_b11, 2048, pd, 1, outB1, 2048);
    // G4: next_b row1 = [X|a1|na00]@w_b00^T where k==0 (na00 staged from next_a row1)
    gemm_k<<<grid, blk, 0, stream>>>(X, 1024, a1, 2048, outA1, 2048,
                                     w_b00, 3072, kbuf, 0, outB1, 2048);
    // G5: next_b row1 = [X|na10]@w_b10^T where k==2
    gemm_k<<<grid, blk, 0, stream>>>(X, 1024, outA1, 2048, nullptr, 0,
                                     w_b10, 2048, kbuf, 2, outB1, 2048);
}

// Round 7
// 502.053 us; speedup vs baseline: 2.2773x; 1.0847x over previous
//
#include <hip/hip_runtime.h>
#include <hip/hip_bf16.h>
#include <stdint.h>
#include <math.h>

typedef unsigned short u16;
typedef __attribute__((ext_vector_type(8))) short frag8;   // 8 bf16 (4 VGPRs)
typedef __attribute__((ext_vector_type(4))) float f32x4;

#define Hdim 1024
#define Brows 4096

// out element offsets (fp32 elements)
#define OUT_B_OFF  8388608   // next_b base
#define OUT_D_OFF 16777216   // next_depth
#define OUT_F_OFF 16781312   // f
#define OUT_J_OFF 16785408   // j

// ---- bf16 workspace layout (u16-element offsets from ws+32KB) ----
#define XB      0u
#define B0B     4194304u
#define A1B     8388608u
#define B1B     12582912u
#define NA00B   16777216u
#define NA10B   20971520u
#define WA00B   25165824u   // 1024x3072
#define WA10B   28311552u   // 1024x2048
#define WB00B   30408704u   // 1024x3072
#define WB11B   33554432u   // 1024x2048
#define WB10B   35651584u   // 1024x2048
#define WS_BF_ELTS 37748736u
#define WS_NEED (32768ull + (unsigned long long)WS_BF_ELTS * 2ull)

__device__ __forceinline__ u16 f2bf(float f) {
    union { float f; unsigned int i; } v; v.f = f;
    unsigned int r = v.i + 0x7fffu + ((v.i >> 16) & 1u);   // RNE
    return (u16)(r >> 16);
}
__device__ __forceinline__ unsigned int pk2(float a, float b) {
    __hip_bfloat162 h = __float22bfloat162_rn(make_float2(a, b));
    union { __hip_bfloat162 h; unsigned int u; } v; v.h = h; return v.u;
}
__device__ __forceinline__ void gl_lds16(const u16* g, u16* l) {
    __builtin_amdgcn_global_load_lds(
        (const __attribute__((address_space(1))) unsigned int*)g,
        (__attribute__((address_space(3))) unsigned int*)l, 16, 0, 0);
}

// ================= fast path: pure-bf16 m97-style GEMM =================
// C[b,n] = sum_k A[b,k]*W[n,k]; A = up to 3 bf16 segments, each contiguous
// (row stride 1024); W bf16 (1024 x K) K-major. Single-buffer LDS,
// global_load_lds width-16 staging, 2-barrier K-loop (m97 structure).
// Epilogue: rows with gate[row]==ksel -> outp fp32; optional bcopy bf16 (all rows).
__global__ __launch_bounds__(256)
void gemm_bf(const u16* __restrict__ a0, const u16* __restrict__ a1p,
             const u16* __restrict__ a2p,
             const u16* __restrict__ W, int K,
             const int* __restrict__ gate, int ksel,
             float* __restrict__ outp, int ostr,
             u16* __restrict__ bcopy)
{
    __shared__ alignas(16) u16 lsA[128 * 64];   // 16 KB
    __shared__ alignas(16) u16 lsB[64 * 64];    // 8 KB

    const int tid  = threadIdx.x;
    const int lane = tid & 63;
    const int wv   = tid >> 6;
    const int wm   = wv >> 1, wn = wv & 1;      // 2x2 waves: 64 rows x 32 cols
    const int m0   = blockIdx.x * 128;
    const int n0   = blockIdx.y * 64;

    f32x4 acc[4][2];
#pragma unroll
    for (int i = 0; i < 4; ++i)
#pragma unroll
        for (int j = 0; j < 2; ++j) acc[i][j] = (f32x4){0.f, 0.f, 0.f, 0.f};

    const u16* segp[3] = { a0, a1p, a2p };

    const int nkt = K / 64;
    for (int kt = 0; kt < nkt; ++kt) {
        const int seg = kt >> 4;
        const int kl  = (kt & 15) * 64;
        const u16* ab = segp[seg] + (size_t)m0 * 1024 + kl;
        const u16* wb = W + (size_t)n0 * K + kt * 64;
        // A: 128x64 bf16 = 1024 16B-chunks, 4/thread
#pragma unroll
        for (int i = 0; i < 4; ++i) {
            const int ch = i * 256 + tid;
            const int r = ch >> 3, c = (ch & 7) * 8;
            gl_lds16(ab + (size_t)r * 1024 + c, &lsA[ch * 8]);
        }
        // B: 64x64 = 512 chunks, 2/thread
#pragma unroll
        for (int i = 0; i < 2; ++i) {
            const int ch = i * 256 + tid;
            const int r = ch >> 3, c = (ch & 7) * 8;
            gl_lds16(wb + (size_t)r * K + c, &lsB[ch * 8]);
        }
        __syncthreads();   // drains vmcnt -> LDS ready
#pragma unroll
        for (int ks = 0; ks < 2; ++ks) {
            const int kc = ks * 32 + (lane >> 4) * 8;
            frag8 af[4], bf[2];
#pragma unroll
            for (int i = 0; i < 4; ++i)
                af[i] = *(const frag8*)&lsA[(wm * 64 + i * 16 + (lane & 15)) * 64 + kc];
#pragma unroll
            for (int j = 0; j < 2; ++j)
                bf[j] = *(const frag8*)&lsB[(wn * 32 + j * 16 + (lane & 15)) * 64 + kc];
#pragma unroll
            for (int i = 0; i < 4; ++i)
#pragma unroll
                for (int j = 0; j < 2; ++j)
                    acc[i][j] = __builtin_amdgcn_mfma_f32_16x16x32_bf16(af[i], bf[j], acc[i][j], 0, 0, 0);
        }
        __syncthreads();   // readers done before next overwrite
    }

    // D layout: row = quad*4 + reg, col = lane&15 (m89-verified)
    const int quad = lane >> 4;
    const int lcol = lane & 15;
#pragma unroll
    for (int i = 0; i < 4; ++i) {
#pragma unroll
        for (int r = 0; r < 4; ++r) {
            const int grow = m0 + wm * 64 + i * 16 + quad * 4 + r;
            const int gv = gate[grow];
#pragma unroll
            for (int j = 0; j < 2; ++j) {
                const int gcol = n0 + wn * 32 + j * 16 + lcol;
                const float v = acc[i][j][r];
                if (bcopy) bcopy[(size_t)grow * 1024 + gcol] = f2bf(v);
                if (gv == ksel) outp[(size_t)grow * ostr + gcol] = v;
            }
        }
    }
}

// ---------- convert_all: fp32 -> bf16 workspace buffers ----------
// One float4 per thread. Flat jobs then strided jobs (row stride 2048 fp32).
__global__ __launch_bounds__(256)
void convert_all(const float* __restrict__ X,
                 const float* __restrict__ prev_a, const float* __restrict__ prev_b,
                 const float* __restrict__ wa00, const float* __restrict__ wa10,
                 const float* __restrict__ wb00, const float* __restrict__ wb11,
                 const float* __restrict__ wb10,
                 u16* __restrict__ ws16)
{
    long long gid = (long long)blockIdx.x * 256 + threadIdx.x;
    const float* src;
    unsigned int dst;
    long long idx;
    if (gid < 1048576) {                        // X
        idx = gid;               src = X + idx * 4;    dst = XB;
    } else if (gid < 1835008) {                 // wa00
        idx = gid - 1048576;     src = wa00 + idx * 4; dst = WA00B;
    } else if (gid < 2359296) {                 // wa10
        idx = gid - 1835008;     src = wa10 + idx * 4; dst = WA10B;
    } else if (gid < 3145728) {                 // wb00
        idx = gid - 2359296;     src = wb00 + idx * 4; dst = WB00B;
    } else if (gid < 3670016) {                 // wb11
        idx = gid - 3145728;     src = wb11 + idx * 4; dst = WB11B;
    } else if (gid < 4194304) {                 // wb10
        idx = gid - 3670016;     src = wb10 + idx * 4; dst = WB10B;
    } else if (gid < 5242880) {                 // b0 (prev_b row-stride 2048)
        idx = gid - 4194304;
        src = prev_b + (idx >> 8) * 2048 + (idx & 255) * 4;          dst = B0B;
    } else if (gid < 6291456) {                 // a1
        idx = gid - 5242880;
        src = prev_a + (idx >> 8) * 2048 + 1024 + (idx & 255) * 4;   dst = A1B;
    } else {                                    // b1
        idx = gid - 6291456;
        src = prev_b + (idx >> 8) * 2048 + 1024 + (idx & 255) * 4;   dst = B1B;
    }
    float4 v = *(const float4*)src;
    uint2 h = { pk2(v.x, v.y), pk2(v.z, v.w) };
    *(uint2*)&ws16[(size_t)dst + idx * 4] = h;
}

// ================= fallback path (proven round-6 GEMM) =================
#define BMf 128
#define BNf 64
#define LDK 72

struct RegTile { float4 a[8]; float4 b[4]; };

__device__ __forceinline__ void load_tile(RegTile& s,
        const float* const* segp, const int* segs,
        const float* __restrict__ W, int K, int kn,
        int m0, int n0, int lr, int lc)
{
    const int seg = kn >> 4;
    const int kl  = (kn & 15) * 64;
    const float* ab = segp[seg];
    const int astr  = segs[seg];
#pragma unroll
    for (int i = 0; i < 8; ++i)
        s.a[i] = *(const float4*)(ab + (size_t)(m0 + i * 16 + lr) * astr + kl + lc);
#pragma unroll
    for (int i = 0; i < 4; ++i)
        s.b[i] = *(const float4*)(W + (size_t)(n0 + i * 16 + lr) * K + kn * 64 + lc);
}
__device__ __forceinline__ void stage_tile(const RegTile& s, u16* LA, u16* LB,
                                           int lr, int lc)
{
#pragma unroll
    for (int i = 0; i < 8; ++i) {
        uint2 h = { pk2(s.a[i].x, s.a[i].y), pk2(s.a[i].z, s.a[i].w) };
        *(uint2*)&LA[(i * 16 + lr) * LDK + lc] = h;
    }
#pragma unroll
    for (int i = 0; i < 4; ++i) {
        uint2 h = { pk2(s.b[i].x, s.b[i].y), pk2(s.b[i].z, s.b[i].w) };
        *(uint2*)&LB[(i * 16 + lr) * LDK + lc] = h;
    }
}
__device__ __forceinline__ void do_mfma_f(const u16* LA, const u16* LB,
                                          int wm, int wn, int lane, f32x4 acc[4][2])
{
#pragma unroll
    for (int ks = 0; ks < 2; ++ks) {
        const int kc = ks * 32 + (lane >> 4) * 8;
        frag8 af[4], bf[2];
#pragma unroll
        for (int i = 0; i < 4; ++i)
            af[i] = *(const frag8*)&LA[(wm * 64 + i * 16 + (lane & 15)) * LDK + kc];
#pragma unroll
        for (int j = 0; j < 2; ++j)
            bf[j] = *(const frag8*)&LB[(wn * 32 + j * 16 + (lane & 15)) * LDK + kc];
#pragma unroll
        for (int i = 0; i < 4; ++i)
#pragma unroll
            for (int j = 0; j < 2; ++j)
                acc[i][j] = __builtin_amdgcn_mfma_f32_16x16x32_bf16(af[i], bf[j], acc[i][j], 0, 0, 0);
    }
}

__global__ __launch_bounds__(256)
void gemm_k(const float* __restrict__ a0, int as0,
            const float* __restrict__ a1p, int as1,
            const float* __restrict__ a2p, int as2,
            const float* __restrict__ W, int K,
            const int* __restrict__ gate, int ksel,
            float* __restrict__ outp, int ostr)
{
    __shared__ alignas(16) u16 lsA[2][BMf * LDK];
    __shared__ alignas(16) u16 lsB[2][BNf * LDK];

    const int tid  = threadIdx.x;
    const int lane = tid & 63;
    const int wv   = tid >> 6;
    const int wm   = wv >> 1, wn = wv & 1;
    const int m0   = blockIdx.x * BMf;
    const int n0   = blockIdx.y * BNf;
    const int lr = tid >> 4;
    const int lc = (tid & 15) * 4;

    f32x4 acc[4][2];
#pragma unroll
    for (int i = 0; i < 4; ++i)
#pragma unroll
        for (int j = 0; j < 2; ++j) acc[i][j] = (f32x4){0.f, 0.f, 0.f, 0.f};

    const float* segp[3] = { a0, a1p, a2p };
    const int    segs[3] = { as0, as1, as2 };

    const int nkt = K / 64;
    RegTile S0, S1;
    load_tile(S0, segp, segs, W, K, 0, m0, n0, lr, lc);
    load_tile(S1, segp, segs, W, K, 1, m0, n0, lr, lc);
    stage_tile(S0, lsA[0], lsB[0], lr, lc);
    __syncthreads();

    for (int kt = 0; kt < nkt; kt += 2) {
        if (kt + 2 < nkt) load_tile(S0, segp, segs, W, K, kt + 2, m0, n0, lr, lc);
        do_mfma_f(lsA[0], lsB[0], wm, wn, lane, acc);
        stage_tile(S1, lsA[1], lsB[1], lr, lc);
        __syncthreads();
        if (kt + 3 < nkt) load_tile(S1, segp, segs, W, K, kt + 3, m0, n0, lr, lc);
        do_mfma_f(lsA[1], lsB[1], wm, wn, lane, acc);
        if (kt + 2 < nkt) {
            stage_tile(S0, lsA[0], lsB[0], lr, lc);
            __syncthreads();
        }
    }

    const int quad = lane >> 4;
    const int lcol = lane & 15;
#pragma unroll
    for (int i = 0; i < 4; ++i) {
#pragma unroll
        for (int r = 0; r < 4; ++r) {
            const int grow = m0 + wm * 64 + i * 16 + quad * 4 + r;
            if (gate[grow] == ksel) {
#pragma unroll
                for (int j = 0; j < 2; ++j) {
                    const int gcol = n0 + wn * 32 + j * 16 + lcol;
                    outp[(size_t)grow * ostr + gcol] = acc[i][j][r];
                }
            }
        }
    }
}

// ---------- prep_u ----------
__global__ __launch_bounds__(256)
void prep_u(const float* __restrict__ w_b11, const float* __restrict__ w_att,
            float* __restrict__ u)
{
    const int k  = (blockIdx.x & 7) * 256 + threadIdx.x;
    const int c0 = (blockIdx.x >> 3) * 128;
    float s0 = 0.f, s3 = 0.f;
    for (int c = c0; c < c0 + 128; ++c) {
        const float w = w_b11[(size_t)c * 2048 + k];
        s0 += w * w_att[7168 + c];
        s3 += w * w_att[3 * 8192 + 7168 + c];
    }
    atomicAdd(&u[k], s0);
    atomicAdd(&u[2048 + k], s3);
}

// ---------- decide ----------
__global__ __launch_bounds__(256)
void decide(const float* __restrict__ X,
            const float* __restrict__ prev_a, const float* __restrict__ prev_b,
            const int* __restrict__ pdin,
            const float* __restrict__ w_att,
            const float* __restrict__ u,
            int* __restrict__ kbuf,
            float* __restrict__ out)
{
    const int lane = threadIdx.x & 63;
    const int wv   = threadIdx.x >> 6;
    const int b    = blockIdx.x * 4 + wv;
    const int pd   = pdin[b];

    const float* a1 = prev_a + (size_t)b * 2048 + 1024;
    const float* b1 = prev_b + (size_t)b * 2048 + 1024;
    const float* xr = X + (size_t)b * 1024;

    int k;
    float fv;
    if (pd == 0) {
        k = 2; fv = 1.f;
    } else {
        float d0 = 0.f, d3 = 0.f;
        const float* w0 = w_att;
        const float* w3 = w_att + 3 * 8192;
        const float* u0 = u;
        const float* u3 = u + 2048;
#pragma unroll
        for (int uu = 0; uu < 2; ++uu) {
            const int c = lane * 16 + uu * 8;
#pragma unroll
            for (int q = 0; q < 2; ++q) {
                const int cc = c + q * 4;
                float4 av = *(const float4*)&a1[cc];
                float4 bv = *(const float4*)&b1[cc];
                float4 xv = *(const float4*)&xr[cc];
                float4 wa0 = *(const float4*)&w0[2048 + cc];
                float4 wb0 = *(const float4*)&w0[3072 + cc];
                float4 wc0 = *(const float4*)&w0[6144 + cc];
                float4 wa3 = *(const float4*)&w3[2048 + cc];
                float4 wb3 = *(const float4*)&w3[3072 + cc];
                float4 wc3 = *(const float4*)&w3[6144 + cc];
                float4 ux0 = *(const float4*)&u0[cc];
                float4 ux3 = *(const float4*)&u3[cc];
                float4 ub0 = *(const float4*)&u0[1024 + cc];
                float4 ub3 = *(const float4*)&u3[1024 + cc];
                d0 += av.x*(wa0.x+wc0.x) + av.y*(wa0.y+wc0.y) + av.z*(wa0.z+wc0.z) + av.w*(wa0.w+wc0.w);
                d3 += av.x*(wa3.x+wc3.x) + av.y*(wa3.y+wc3.y) + av.z*(wa3.z+wc3.z) + av.w*(wa3.w+wc3.w);
                d0 += bv.x*wb0.x + bv.y*wb0.y + bv.z*wb0.z + bv.w*wb0.w;
                d3 += bv.x*wb3.x + bv.y*wb3.y + bv.z*wb3.z + bv.w*wb3.w;
                d0 += xv.x*ux0.x + xv.y*ux0.y + xv.z*ux0.z + xv.w*ux0.w;
                d3 += xv.x*ux3.x + xv.y*ux3.y + xv.z*ux3.z + xv.w*ux3.w;
                d0 += bv.x*ub0.x + bv.y*ub0.y + bv.z*ub0.z + bv.w*ub0.w;
                d3 += bv.x*ub3.x + bv.y*ub3.y + bv.z*ub3.z + bv.w*ub3.w;
            }
        }
#pragma unroll
        for (int off = 32; off; off >>= 1) {
            d0 += __shfl_xor(d0, off, 64);
            d3 += __shfl_xor(d3, off, 64);
        }
        k = (d3 > d0) ? 3 : 0;
        fv = (k == 3) ? 1.f : 0.f;
    }
    const float jv = (pd == 0) ? 0.f : fv;
    const int nd = (k == 2) ? pd + 1 : pd;

    float* outA = out;
    float* outB = out + OUT_B_OFF;

    const float4 z4 = make_float4(0.f, 0.f, 0.f, 0.f);
#pragma unroll
    for (int uu = 0; uu < 4; ++uu) {
        const int c = lane * 16 + uu * 4;
        *(float4*)&outA[(size_t)b * 2048 + c] = z4;
        *(float4*)&outB[(size_t)b * 2048 + c] = z4;
    }
    if (k == 3) {
#pragma unroll
        for (int uu = 0; uu < 4; ++uu) {
            const int c = lane * 16 + uu * 4;
            *(float4*)&outA[(size_t)b * 2048 + 1024 + c] = *(const float4*)&a1[c];
        }
    }
    if (lane == 0) {
        kbuf[b] = k;
        out[OUT_D_OFF + b] = (float)nd;
        out[OUT_F_OFF + b] = fv;
        out[OUT_J_OFF + b] = jv;
    }
}

// ---------- launch ----------
extern "C" void kernel_launch(void* const* d_in, const int* in_sizes, int n_in,
                              void* d_out, int out_size, void* d_ws, size_t ws_size,
                              hipStream_t stream)
{
    const float* X      = (const float*)d_in[0];
    const float* prev_a = (const float*)d_in[3];
    const float* prev_b = (const float*)d_in[4];
    const int*   pd     = (const int*)d_in[5];
    const float* w_a00  = (const float*)d_in[6];
    const float* w_a10  = (const float*)d_in[7];
    const float* w_b00  = (const float*)d_in[8];
    const float* w_b11  = (const float*)d_in[9];
    const float* w_b10  = (const float*)d_in[10];
    const float* w_att  = (const float*)d_in[12];

    float* u    = (float*)d_ws;                        // 16 KB
    int*   kbuf = (int*)((char*)d_ws + 16384);         // 16 KB

    const float* a1 = prev_a + 1024;
    const float* b0 = prev_b;
    const float* b1 = prev_b + 1024;

    float* out   = (float*)d_out;
    float* outA1 = out + 1024;
    float* outB1 = out + OUT_B_OFF + 1024;

    dim3 blk(256);

    hipMemsetAsync(u, 0, 16384, stream);
    prep_u<<<dim3(64), blk, 0, stream>>>(w_b11, w_att, u);
    decide<<<dim3(Brows / 4), blk, 0, stream>>>(X, prev_a, prev_b, pd, w_att, u, kbuf, out);

    if (ws_size >= WS_NEED) {
        // ---- fast path: pre-convert to bf16, m97-style GEMMs ----
        u16* ws16 = (u16*)((char*)d_ws + 32768);
        convert_all<<<dim3(28672), blk, 0, stream>>>(X, prev_a, prev_b,
            w_a00, w_a10, w_b00, w_b11, w_b10, ws16);

        dim3 grid(Brows / 128, Hdim / 64);
        // G1: na00 -> next_a row1 (k==0) + bf16 copy (all rows)
        gemm_bf<<<grid, blk, 0, stream>>>(ws16 + XB, ws16 + B0B, ws16 + A1B,
            ws16 + WA00B, 3072, kbuf, 0, outA1, 2048, ws16 + NA00B);
        // G2: na10 -> next_a row1 (k==2) + bf16 copy
        gemm_bf<<<grid, blk, 0, stream>>>(ws16 + XB, ws16 + B0B, nullptr,
            ws16 + WA10B, 2048, kbuf, 2, outA1, 2048, ws16 + NA10B);
        // G3: nb11 -> next_b row1 (pd==1; k==0 rows overwritten by G4)
        gemm_bf<<<grid, blk, 0, stream>>>(ws16 + XB, ws16 + B1B, nullptr,
            ws16 + WB11B, 2048, pd, 1, outB1, 2048, nullptr);
        // G4: nb00 -> next_b row1 (k==0)
        gemm_bf<<<grid, blk, 0, stream>>>(ws16 + XB, ws16 + A1B, ws16 + NA00B,
            ws16 + WB00B, 3072, kbuf, 0, outB1, 2048, nullptr);
        // G5: nb10 -> next_b row1 (k==2)
        gemm_bf<<<grid, blk, 0, stream>>>(ws16 + XB, ws16 + NA10B, nullptr,
            ws16 + WB10B, 2048, kbuf, 2, outB1, 2048, nullptr);
    } else {
        // ---- fallback: proven round-6 fp32-staging path ----
        dim3 grid(Brows / BMf, Hdim / BNf);
        gemm_k<<<grid, blk, 0, stream>>>(X, 1024, b0, 2048, a1, 2048,
                                         w_a00, 3072, kbuf, 0, outA1, 2048);
        gemm_k<<<grid, blk, 0, stream>>>(X, 1024, b0, 2048, nullptr, 0,
                                         w_a10, 2048, kbuf, 2, outA1, 2048);
        gemm_k<<<grid, blk, 0, stream>>>(X, 1024, b1, 2048, nullptr, 0,
                                         w_b11, 2048, pd, 1, outB1, 2048);
        gemm_k<<<grid, blk, 0, stream>>>(X, 1024, a1, 2048, outA1, 2048,
                                         w_b00, 3072, kbuf, 0, outB1, 2048);
        gemm_k<<<grid, blk, 0, stream>>>(X, 1024, outA1, 2048, nullptr, 0,
                                         w_b10, 2048, kbuf, 2, outB1, 2048);
    }
}